// Round 2
// baseline (44.533 us; speedup 1.0000x reference)
//
#include <hip/hip_runtime.h>

// DepthLoss: loss = mean over {d>0} of |img[b,0,r,c] - d|, single f32 scalar.
// B=32, N=16384, H=768, W=1024. rdepth layout [B][N][3] = (row, col, d) f32.
//
// Single fused kernel: per-block partials + threadfence/atomic ticket;
// the last-arriving block reduces all partials in a FIXED order (deterministic
// regardless of which block finalizes). 4-byte flag zeroed per launch via
// hipMemsetAsync (graph-capture safe).

#define TPB 256
#define EPT 2   // elements per thread: 2 elems = 6 floats = 3x float2 (8B-aligned)

constexpr int kN  = 16384;
constexpr int kH  = 768;
constexpr int kW  = 1024;
constexpr int kHW = kH * kW;

__global__ __launch_bounds__(TPB) void depthloss_fused(
    const float* __restrict__ img,       // [B*H*W]
    const float2* __restrict__ rd2,      // B*N*3/2 float2s
    float2* __restrict__ partials,       // [nblocks]
    unsigned int* __restrict__ flag,     // zeroed before launch
    float* __restrict__ out,
    int nelem, int nblocks)
{
    int tid = blockIdx.x * blockDim.x + threadIdx.x;
    int e0  = tid * EPT;

    float loss = 0.f, cnt = 0.f;
    if (e0 < nelem) {
        int b = e0 / kN;                 // EPT divides N, pair never crosses b
        const float* base = img + (long)b * kHW;

        float2 f0 = rd2[tid * 3 + 0];
        float2 f1 = rd2[tid * 3 + 1];
        float2 f2 = rd2[tid * 3 + 2];
        float r0 = f0.x, c0 = f0.y, d0 = f1.x;
        float r1 = f1.y, c1 = f2.x, d1 = f2.y;

        bool m0 = d0 > 0.f, m1 = d1 > 0.f;
        if (m0) { loss += fabsf(base[(int)r0 * kW + (int)c0] - d0); cnt += 1.f; }
        if (m1) { loss += fabsf(base[(int)r1 * kW + (int)c1] - d1); cnt += 1.f; }
    }

    // 64-lane wave reduction
    #pragma unroll
    for (int off = 32; off > 0; off >>= 1) {
        loss += __shfl_down(loss, off);
        cnt  += __shfl_down(cnt,  off);
    }

    __shared__ float2 lds[TPB / 64];
    __shared__ int isLast;
    int lane = threadIdx.x & 63;
    int wid  = threadIdx.x >> 6;
    if (lane == 0) lds[wid] = make_float2(loss, cnt);
    __syncthreads();

    if (threadIdx.x == 0) {
        float L = 0.f, C = 0.f;
        #pragma unroll
        for (int w = 0; w < TPB / 64; ++w) { L += lds[w].x; C += lds[w].y; }
        partials[blockIdx.x] = make_float2(L, C);
        __threadfence();                          // release partials (agent scope)
        unsigned int old = atomicAdd(flag, 1u);
        isLast = (old == (unsigned int)(nblocks - 1));
    }
    __syncthreads();

    if (isLast) {
        __threadfence();                          // acquire: see all partials
        float L = 0.f, C = 0.f;
        for (int i = threadIdx.x; i < nblocks; i += TPB) {   // fixed order
            float2 p = partials[i];
            L += p.x; C += p.y;
        }
        #pragma unroll
        for (int off = 32; off > 0; off >>= 1) {
            L += __shfl_down(L, off);
            C += __shfl_down(C, off);
        }
        if (lane == 0) lds[wid] = make_float2(L, C);
        __syncthreads();
        if (threadIdx.x == 0) {
            float l = 0.f, c = 0.f;
            #pragma unroll
            for (int w = 0; w < TPB / 64; ++w) { l += lds[w].x; c += lds[w].y; }
            out[0] = (c > 0.f) ? (l / c) : 0.f;
        }
    }
}

extern "C" void kernel_launch(void* const* d_in, const int* in_sizes, int n_in,
                              void* d_out, int out_size, void* d_ws, size_t ws_size,
                              hipStream_t stream) {
    const float* img    = (const float*)d_in[0];   // (B,1,H,W) f32
    const float* rdepth = (const float*)d_in[1];   // (B,N,3)  f32
    float* out = (float*)d_out;

    int nelem    = in_sizes[1] / 3;                 // 524288
    int nthreads = nelem / EPT;                     // 262144
    int nblocks  = (nthreads + TPB - 1) / TPB;      // 1024

    float2* partials  = (float2*)d_ws;                                  // 8 KB
    unsigned int* flg = (unsigned int*)((char*)d_ws + (size_t)nblocks * sizeof(float2));

    hipMemsetAsync(flg, 0, sizeof(unsigned int), stream);
    depthloss_fused<<<nblocks, TPB, 0, stream>>>(
        img, (const float2*)rdepth, partials, flg, out, nelem, nblocks);
}

// Round 3
// 16.358 us; speedup vs baseline: 2.7224x; 2.7224x over previous
//
#include <hip/hip_runtime.h>

// DepthLoss: loss = mean over {d>0} of |img[b,0,r,c] - d|, single f32 scalar.
// B=32, N=16384, H=768, W=1024. rdepth layout [B][N][3] = (row, col, d) f32.
//
// Two-kernel deterministic reduction (no atomics, no fences, no memset):
//   pass1: 1024 blocks x 256 thr, EPT=2; per-wave shfl reduce; lane0 of each
//          wave writes a float2 partial (4096 total, 32 KB in d_ws).
//   pass2: single 1024-thread block reduces the 4096 partials in fixed order.

#define TPB 256
#define EPT 2      // 2 elems = 6 floats = 3x float2 (8B-aligned)

constexpr int kN  = 16384;
constexpr int kH  = 768;
constexpr int kW  = 1024;
constexpr int kHW = kH * kW;

__global__ __launch_bounds__(TPB) void depthloss_pass1(
    const float* __restrict__ img,       // [B*H*W]
    const float2* __restrict__ rd2,      // B*N*3/2 float2s
    float2* __restrict__ partials,       // [nblocks * TPB/64]
    int nelem)
{
    int tid = blockIdx.x * blockDim.x + threadIdx.x;
    int e0  = tid * EPT;

    float loss = 0.f, cnt = 0.f;
    if (e0 < nelem) {
        int b = e0 / kN;                 // EPT divides N: pair never crosses b
        const float* base = img + (long)b * kHW;

        float2 f0 = rd2[tid * 3 + 0];
        float2 f1 = rd2[tid * 3 + 1];
        float2 f2 = rd2[tid * 3 + 2];
        float r0 = f0.x, c0 = f0.y, d0 = f1.x;
        float r1 = f1.y, c1 = f2.x, d1 = f2.y;

        if (d0 > 0.f) { loss += fabsf(base[(int)r0 * kW + (int)c0] - d0); cnt += 1.f; }
        if (d1 > 0.f) { loss += fabsf(base[(int)r1 * kW + (int)c1] - d1); cnt += 1.f; }
    }

    // 64-lane wave reduction
    #pragma unroll
    for (int off = 32; off > 0; off >>= 1) {
        loss += __shfl_down(loss, off);
        cnt  += __shfl_down(cnt,  off);
    }

    int lane = threadIdx.x & 63;
    int wid  = threadIdx.x >> 6;
    if (lane == 0)
        partials[blockIdx.x * (TPB / 64) + wid] = make_float2(loss, cnt);
}

__global__ __launch_bounds__(1024) void depthloss_pass2(
    const float2* __restrict__ partials, float* __restrict__ out, int np)
{
    int t = threadIdx.x;
    float L = 0.f, C = 0.f;
    for (int i = t; i < np; i += 1024) {     // fixed order -> deterministic
        float2 p = partials[i];
        L += p.x; C += p.y;
    }

    #pragma unroll
    for (int off = 32; off > 0; off >>= 1) {
        L += __shfl_down(L, off);
        C += __shfl_down(C, off);
    }

    __shared__ float2 lds[16];
    int lane = t & 63;
    int wid  = t >> 6;
    if (lane == 0) lds[wid] = make_float2(L, C);
    __syncthreads();

    if (t == 0) {
        float l = 0.f, c = 0.f;
        #pragma unroll
        for (int w = 0; w < 16; ++w) { l += lds[w].x; c += lds[w].y; }
        out[0] = (c > 0.f) ? (l / c) : 0.f;
    }
}

extern "C" void kernel_launch(void* const* d_in, const int* in_sizes, int n_in,
                              void* d_out, int out_size, void* d_ws, size_t ws_size,
                              hipStream_t stream) {
    const float* img    = (const float*)d_in[0];   // (B,1,H,W) f32
    const float* rdepth = (const float*)d_in[1];   // (B,N,3)  f32
    float* out = (float*)d_out;

    int nelem    = in_sizes[1] / 3;                 // 524288
    int nthreads = nelem / EPT;                     // 262144
    int nblocks  = (nthreads + TPB - 1) / TPB;      // 1024
    int np       = nblocks * (TPB / 64);            // 4096 partials

    float2* partials = (float2*)d_ws;               // 32 KB

    depthloss_pass1<<<nblocks, TPB, 0, stream>>>(
        img, (const float2*)rdepth, partials, nelem);
    depthloss_pass2<<<1, 1024, 0, stream>>>(partials, out, np);
}

// Round 5
// 12.965 us; speedup vs baseline: 3.4349x; 1.2617x over previous
//
#include <hip/hip_runtime.h>

// DepthLoss: loss = mean over {d>0} of |img[b,0,r,c] - d|, single f32 scalar.
// B=32, N=16384, H=768, W=1024. rdepth layout [B][N][3] = (row, col, d) f32.
//
// pass1: 512 blocks x 256 thr, EPT=4. XCD-chunked swizzle: virtual block
//        vb = (bi%8)*64 + bi/8 so each XCD (bi%8) works on only 4 of the 32
//        b-slices (12 MB vs 96 MB through its 4 MB L2). rdepth loads are
//        nontemporal (pure stream, don't evict the gather working set).
//        Per-block LDS reduce -> 512 float2 partials.
// pass2: one 512-thread block, fixed-order reduce -> deterministic.

#define TPB 256
#define EPT 4      // 4 elems = 12 floats = 3x float4 (16B-aligned)

constexpr int kN  = 16384;
constexpr int kH  = 768;
constexpr int kW  = 1024;
constexpr int kHW = kH * kW;

typedef float floatx4 __attribute__((ext_vector_type(4)));  // native vec for nontemporal builtin

__global__ __launch_bounds__(TPB) void depthloss_pass1(
    const float* __restrict__ img,        // [B*H*W]
    const floatx4* __restrict__ rd4,      // B*N*3/4 float4s
    float2* __restrict__ partials,        // [gridDim.x]
    int nelem)
{
    // XCD-chunked swizzle (gridDim.x = 512 = 8*64, divides evenly -> bijective)
    int bi = blockIdx.x;
    int vb = (bi & 7) * 64 + (bi >> 3);

    int vtid = vb * TPB + threadIdx.x;
    int e0   = vtid * EPT;                // block covers 1024 contiguous elems

    float loss = 0.f, cnt = 0.f;
    if (e0 < nelem) {
        int b = e0 / kN;                  // uniform per block (1024 | 16384)
        const float* base = img + (long)b * kHW;

        floatx4 f0 = __builtin_nontemporal_load(&rd4[vtid * 3 + 0]);
        floatx4 f1 = __builtin_nontemporal_load(&rd4[vtid * 3 + 1]);
        floatx4 f2 = __builtin_nontemporal_load(&rd4[vtid * 3 + 2]);

        float r[4] = {f0.x, f0.w, f1.z, f2.y};
        float c[4] = {f0.y, f1.x, f1.w, f2.z};
        float d[4] = {f0.z, f1.y, f2.x, f2.w};

        // issue all 4 gathers (exec-masked) before accumulating
        float v[4];
        #pragma unroll
        for (int k = 0; k < 4; ++k)
            v[k] = (d[k] > 0.f) ? base[(int)r[k] * kW + (int)c[k]] : 0.f;

        #pragma unroll
        for (int k = 0; k < 4; ++k) {
            if (d[k] > 0.f) { loss += fabsf(v[k] - d[k]); cnt += 1.f; }
        }
    }

    // 64-lane wave reduction
    #pragma unroll
    for (int off = 32; off > 0; off >>= 1) {
        loss += __shfl_down(loss, off);
        cnt  += __shfl_down(cnt,  off);
    }

    __shared__ float2 lds[TPB / 64];
    int lane = threadIdx.x & 63;
    int wid  = threadIdx.x >> 6;
    if (lane == 0) lds[wid] = make_float2(loss, cnt);
    __syncthreads();

    if (threadIdx.x == 0) {
        float L = 0.f, C = 0.f;
        #pragma unroll
        for (int w = 0; w < TPB / 64; ++w) { L += lds[w].x; C += lds[w].y; }
        partials[blockIdx.x] = make_float2(L, C);
    }
}

__global__ __launch_bounds__(512) void depthloss_pass2(
    const float2* __restrict__ partials, float* __restrict__ out, int np)
{
    int t = threadIdx.x;
    float L = 0.f, C = 0.f;
    if (t < np) { float2 p = partials[t]; L = p.x; C = p.y; }

    #pragma unroll
    for (int off = 32; off > 0; off >>= 1) {
        L += __shfl_down(L, off);
        C += __shfl_down(C, off);
    }

    __shared__ float2 lds[8];
    int lane = t & 63;
    int wid  = t >> 6;
    if (lane == 0) lds[wid] = make_float2(L, C);
    __syncthreads();

    if (t == 0) {
        float l = 0.f, c = 0.f;
        #pragma unroll
        for (int w = 0; w < 8; ++w) { l += lds[w].x; c += lds[w].y; }
        out[0] = (c > 0.f) ? (l / c) : 0.f;
    }
}

extern "C" void kernel_launch(void* const* d_in, const int* in_sizes, int n_in,
                              void* d_out, int out_size, void* d_ws, size_t ws_size,
                              hipStream_t stream) {
    const float* img    = (const float*)d_in[0];   // (B,1,H,W) f32
    const float* rdepth = (const float*)d_in[1];   // (B,N,3)  f32
    float* out = (float*)d_out;

    int nelem    = in_sizes[1] / 3;                 // 524288
    int nthreads = nelem / EPT;                     // 131072
    int nblocks  = (nthreads + TPB - 1) / TPB;      // 512

    float2* partials = (float2*)d_ws;               // 4 KB

    depthloss_pass1<<<nblocks, TPB, 0, stream>>>(
        img, (const floatx4*)rdepth, partials, nelem);
    depthloss_pass2<<<1, 512, 0, stream>>>(partials, out, nblocks);
}